// Round 2
// baseline (782.779 us; speedup 1.0000x reference)
//
#include <hip/hip_runtime.h>
#include <cstdint>
#include <cstddef>

typedef _Float16 f16;
typedef _Float16 f16x8 __attribute__((ext_vector_type(8)));
typedef float f32x4 __attribute__((ext_vector_type(4)));

// ---------------- helpers ----------------

__device__ __forceinline__ uint32_t packh2(float a, float b) {
  f16 ha = (f16)a, hb = (f16)b;
  uint16_t ua = __builtin_bit_cast(uint16_t, ha);
  uint16_t ub = __builtin_bit_cast(uint16_t, hb);
  return (uint32_t)ua | ((uint32_t)ub << 16);
}

// ---------------- prep: LUT^T fp16, centroid sq-norms, BN consts, pool zero ----------------
// lutT[o][c*16+k] = sum_s cent[c,k,s] * wsub[c,s,o]
__global__ __launch_bounds__(256) void prep_kernel(
    const float* __restrict__ cent1, const float* __restrict__ wsub1,
    const float* __restrict__ cent2, const float* __restrict__ wsub2,
    const float* __restrict__ g1, const float* __restrict__ be1,
    const float* __restrict__ mu1, const float* __restrict__ va1,
    const float* __restrict__ g2, const float* __restrict__ be2,
    const float* __restrict__ mu2, const float* __restrict__ va2,
    f16* __restrict__ lut1T, f16* __restrict__ lut2T,
    float* __restrict__ cn1, float* __restrict__ cn2,
    float* __restrict__ bn1i, float* __restrict__ bn1a,
    float* __restrict__ bn2i, float* __restrict__ bn2a,
    float* __restrict__ pool)
{
  int bx = blockIdx.x, t = threadIdx.x;
  if (bx < 8192) {
    int conv = bx >> 12, ck = bx & 4095, c = ck >> 4;
    const float* cent = conv ? cent2 : cent1;
    const float* wsub = conv ? wsub2 : wsub1;
    f16* lutT = conv ? lut2T : lut1T;
    float s = 0.f;
#pragma unroll
    for (int sv = 0; sv < 9; ++sv)
      s += cent[ck*9 + sv] * wsub[(c*9 + sv)*256 + t];
    lutT[(size_t)t*4096 + ck] = (f16)s;
  } else {
    for (int j = 0; j < 16; ++j) {
      int ck = j*256 + t;
      float s1 = 0.f, s2 = 0.f;
#pragma unroll
      for (int sv = 0; sv < 9; ++sv) {
        float a = cent1[ck*9 + sv]; s1 += a*a;
        float b = cent2[ck*9 + sv]; s2 += b*b;
      }
      cn1[ck] = s1; cn2[ck] = s2;
      pool[ck] = 0.f;                 // ws is re-poisoned 0xAA every launch
    }
    float i1 = g1[t] * rsqrtf(va1[t] + 1e-5f);
    bn1i[t] = i1; bn1a[t] = be1[t] - mu1[t]*i1;
    float i2 = g2[t] * rsqrtf(va2[t] + 1e-5f);
    bn2i[t] = i2; bn2a[t] = be2[t] - mu2[t]*i2;
  }
}

// ---------------- fused attn+GEMM layer ----------------
// Never materializes the [12544, 4096] attn matrix (was 2x ~205 MB HBM round
// trip). Block = 64 output rows (positions) x all 256 outputs, K = 4096.
// Per K-chunk of 64 (= 4 channels x 16 codewords):
//   - 512 threads produce the 64x64 fp16 attn tile: 2 threads per
//     (pos, channel) pair (8 codewords each; softmax max/sum combined via
//     __shfl_xor(.,1)), XOR-swizzled ds_write_b128 into a 16 KB LDS A-buffer
//     (double buffered).
//   - 8 waves (2x4 grid, wave tile 32x64) run mfma_f32_16x16x32_f16 reading
//     A-fragments from LDS (swizzle: physical 16B-chunk p of row r holds
//     logical p^(r&7); readers use ((ks*4+fq)^(fm&7)) -> conflict-free) and
//     B-fragments DIRECTLY from global lutT (2 MB total, shared by all
//     blocks -> per-XCD L2 resident; no B staging, no vmcnt(0) drain cost).
// One barrier per K-iter. Patch loads for chunk k+1 are issued before the
// MFMA phase so HBM/L2 latency hides under compute; masks applied at use so
// the waitcnt lands in the attn phase, not before the MFMAs.
// SRC==0: src is x, NCHW [16][256][28][28]. SRC==1: src is y1, NHWC [12544][256].
template<int SRC, bool RELU>
__global__ __launch_bounds__(512, 2) void fused_kernel(
    const float* __restrict__ src, const float* __restrict__ cent,
    const float* __restrict__ cn, const f16* __restrict__ lutT,
    const float* __restrict__ inv, const float* __restrict__ add,
    float* __restrict__ Y)
{
  __shared__ __align__(16) f16 As[2][64*64];    // 2 x 8 KB double buffer

  int t = threadIdx.x;
  int lane = t & 63, wave = t >> 6;
  int wm = wave >> 2, wn = wave & 3;            // 2x4 wave grid, tile 32x64
  int fm = lane & 15, fq = lane >> 4;

  // attn producer role: pair (pos, cg) split across 2 adjacent lanes (half)
  int pos = t >> 3;             // 0..63
  int cg  = (t >> 1) & 3;       // channel within 4-channel K-chunk
  int half = t & 1;             // codeword half: k = half*8 .. half*8+7
  int row0 = blockIdx.x * 64;
  int P = row0 + pos;
  int b = P / 784, n = P % 784, h = n / 28, w = n % 28;

  const float* pb[9]; float msk[9];
  {
    int offc[9];
#pragma unroll
    for (int dh = 0; dh < 3; ++dh)
#pragma unroll
      for (int dw = 0; dw < 3; ++dw) {
        int hh = h + dh - 1, ww = w + dw - 1;
        bool ok = (hh >= 0) && (hh < 28) && (ww >= 0) && (ww < 28);
        offc[dh*3+dw] = ok ? (hh*28 + ww) : 0;
        msk[dh*3+dw] = ok ? 1.f : 0.f;
      }
#pragma unroll
    for (int s = 0; s < 9; ++s)
      pb[s] = (SRC == 0) ? src + ((size_t)b*256 + cg)*784 + offc[s]
                         : src + ((size_t)b*784 + offc[s])*256 + cg;
  }
  const int pstep = (SRC == 0) ? 4*784 : 4;     // advance to channel c+4
  const float* cb  = cent + (size_t)cg*144 + half*72;  // + kt*576 per chunk
  const float* cnp = cn + cg*16 + half*8;              // + kt*64 per chunk

  f32x4 acc[2][4] = {};

  auto attn_store = [&](int kt, const float* pn, f16* Ab) {
    float p[9];
#pragma unroll
    for (int s = 0; s < 9; ++s) p[s] = pn[s]*msk[s];
    // 8 centroid rows x 9 = 72 contiguous floats -> 18 vec4 loads (broadcast
    // across the 8 lanes sharing (cg,half); L1-resident)
    const float* ce = cb + (size_t)kt*576;
    f32x4 cr[18];
#pragma unroll
    for (int i = 0; i < 18; ++i) cr[i] = *(const f32x4*)(ce + i*4);
    f32x4 c0 = *(const f32x4*)(cnp + kt*64);
    f32x4 c1 = *(const f32x4*)(cnp + kt*64 + 4);
    float e[8];
#pragma unroll
    for (int k = 0; k < 8; ++k) {
      float dot = 0.f;
#pragma unroll
      for (int s = 0; s < 9; ++s) {
        int i = k*9 + s;                        // compile-time after unroll
        dot += p[s]*cr[i >> 2][i & 3];
      }
      e[k] = 2.f*dot - (k < 4 ? c0[k] : c1[k-4]);  // ||p||^2 cancels in softmax
    }
    float mx = e[0];
#pragma unroll
    for (int k = 1; k < 8; ++k) mx = fmaxf(mx, e[k]);
    mx = fmaxf(mx, __shfl_xor(mx, 1));          // pair-combine (same wave)
    float sum = 0.f;
#pragma unroll
    for (int k = 0; k < 8; ++k) { e[k] = __expf(e[k] - mx); sum += e[k]; }
    sum += __shfl_xor(sum, 1);
    float rs = 1.f/sum;
    uint32_t w0 = packh2(e[0]*rs, e[1]*rs);
    uint32_t w1 = packh2(e[2]*rs, e[3]*rs);
    uint32_t w2 = packh2(e[4]*rs, e[5]*rs);
    uint32_t w3 = packh2(e[6]*rs, e[7]*rs);
    // logical chunk cg*2+half of row pos, stored at physical chunk ^(pos&7);
    // 8 lanes of a group cover one full 128B row -> conflict-free b128 write
    int chunk = (cg*2 + half) ^ (pos & 7);
    *(uint4*)(Ab + pos*64 + chunk*8) = make_uint4(w0, w1, w2, w3);
  };

  auto compute = [&](const f16* Ab, int kt) {
#pragma unroll
    for (int ks = 0; ks < 2; ++ks) {
      int co = ((ks*4 + fq) ^ (fm & 7)) * 8;
      f16x8 af[2];
#pragma unroll
      for (int m = 0; m < 2; ++m)
        af[m] = *(const f16x8*)(Ab + (wm*32 + m*16 + fm)*64 + co);
      f16x8 bf[4];
#pragma unroll
      for (int nn = 0; nn < 4; ++nn)
        bf[nn] = *(const f16x8*)(lutT + (size_t)(wn*64 + nn*16 + fm)*4096
                                 + kt*64 + (ks*4 + fq)*8);
#pragma unroll
      for (int m = 0; m < 2; ++m)
#pragma unroll
        for (int nn = 0; nn < 4; ++nn)
          acc[m][nn] = __builtin_amdgcn_mfma_f32_16x16x32_f16(af[m], bf[nn], acc[m][nn], 0, 0, 0);
    }
  };

  {
    float pn[9];
#pragma unroll
    for (int s = 0; s < 9; ++s) pn[s] = pb[s][0];
    attn_store(0, pn, As[0]);
  }
#pragma unroll 1
  for (int kt = 0; kt < 64; ++kt) {
    f16* Ac = As[kt & 1];
    f16* An = As[(kt & 1) ^ 1];
    __syncthreads();                  // A(kt) writes visible; An free (mfma kt-1 done)
    float pn[9];
    if (kt < 63) {
#pragma unroll
      for (int s = 0; s < 9; ++s) pn[s] = pb[s][(kt + 1)*pstep];  // latency hides under MFMA
    }
    compute(Ac, kt);
    if (kt < 63) attn_store(kt + 1, pn, An);
  }

  // epilogue: C/D layout col=lane&15, row=fq*4+r; fused BN (+ReLU)
#pragma unroll
  for (int nn = 0; nn < 4; ++nn) {
    int colg = wn*64 + nn*16 + fm;
    float iv = inv[colg], ad = add[colg];
#pragma unroll
    for (int m = 0; m < 2; ++m) {
      int rowg = row0 + wm*32 + m*16 + fq*4;
#pragma unroll
      for (int r = 0; r < 4; ++r) {
        float v = acc[m][nn][r]*iv + ad;
        if (RELU) v = fmaxf(v, 0.f);
        Y[(size_t)(rowg + r)*256 + colg] = v;
      }
    }
  }
}

// ---------------- global average pool (partial sums, atomics) ----------------
__global__ __launch_bounds__(256) void pool_kernel(const float* __restrict__ y2,
                                                   float* __restrict__ pool)
{
  int b = blockIdx.x, t = threadIdx.x;
  int r0 = blockIdx.y * 112;
  float s = 0.f;
  for (int r = 0; r < 112; ++r)
    s += y2[((size_t)b*784 + r0 + r)*256 + t];
  atomicAdd(&pool[b*256 + t], s);
}

// ---------------- SE MLP: scale = sigmoid(relu(mean @ w1 + b1) @ w2 + b2) ----------------
__global__ __launch_bounds__(256) void se_kernel(
    const float* __restrict__ pool, const float* __restrict__ w1, const float* __restrict__ b1,
    const float* __restrict__ w2, const float* __restrict__ b2, float* __restrict__ scale)
{
  __shared__ float m[256];
  __shared__ float hbuf[16];
  int b = blockIdx.x, t = threadIdx.x;
  m[t] = pool[b*256 + t] * (1.f/784.f);
  __syncthreads();
  if (t < 16) {
    float a = b1[t];
    for (int o = 0; o < 256; ++o) a += m[o]*w1[o*16 + t];
    hbuf[t] = fmaxf(a, 0.f);
  }
  __syncthreads();
  float a = b2[t];
#pragma unroll
  for (int jj = 0; jj < 16; ++jj) a += hbuf[jj]*w2[jj*256 + t];
  scale[b*256 + t] = 1.f/(1.f + __expf(-a));
}

// ---------------- final: out = relu(y2 * scale + x), NCHW ----------------
__global__ __launch_bounds__(256) void final_kernel(
    const float* __restrict__ y2, const float* __restrict__ scale,
    const float* __restrict__ x, float* __restrict__ out)
{
  int idx = blockIdx.x*256 + threadIdx.x;
  int b = idx / 200704, rem = idx % 200704;
  int o = rem / 784, hw = rem % 784;
  float v = y2[((size_t)b*784 + hw)*256 + o]*scale[b*256 + o] + x[idx];
  out[idx] = fmaxf(v, 0.f);
}

// ---------------- launch ----------------
extern "C" void kernel_launch(void* const* d_in, const int* in_sizes, int n_in,
                              void* d_out, int out_size, void* d_ws, size_t ws_size,
                              hipStream_t stream) {
  const float* x     = (const float*)d_in[0];
  const float* cent1 = (const float*)d_in[1];
  const float* wsub1 = (const float*)d_in[2];
  const float* g1    = (const float*)d_in[3];
  const float* be1   = (const float*)d_in[4];
  const float* mu1   = (const float*)d_in[5];
  const float* va1   = (const float*)d_in[6];
  const float* cent2 = (const float*)d_in[7];
  const float* wsub2 = (const float*)d_in[8];
  const float* g2    = (const float*)d_in[9];
  const float* be2   = (const float*)d_in[10];
  const float* mu2   = (const float*)d_in[11];
  const float* va2   = (const float*)d_in[12];
  const float* sw1   = (const float*)d_in[13];
  const float* sb1   = (const float*)d_in[14];
  const float* sw2   = (const float*)d_in[15];
  const float* sb2   = (const float*)d_in[16];
  float* out = (float*)d_out;

  char* ws = (char*)d_ws;
  // attn region (first ~102.8 MB) now unused — kept offsets to minimize churn
  f16*   lut1T = (f16*)(ws + 102760448);          // 2 MB
  f16*   lut2T = (f16*)(ws + 104857600);          // 2 MB
  float* y1    = (float*)(ws + 106954752);        // 12,845,056
  float* y2    = (float*)(ws + 119799808);        // 12,845,056
  float* cn1   = (float*)(ws + 132644864);        // 16 KB
  float* cn2   = (float*)(ws + 132661248);        // 16 KB
  float* bn1i  = (float*)(ws + 132677632);
  float* bn1a  = (float*)(ws + 132678656);
  float* bn2i  = (float*)(ws + 132679680);
  float* bn2a  = (float*)(ws + 132680704);
  float* pool  = (float*)(ws + 132681728);        // 16 KB
  float* scale = (float*)(ws + 132698112);        // 16 KB  (end ~126.6 MiB)

  prep_kernel<<<8193, 256, 0, stream>>>(cent1, wsub1, cent2, wsub2,
                                        g1, be1, mu1, va1, g2, be2, mu2, va2,
                                        lut1T, lut2T, cn1, cn2,
                                        bn1i, bn1a, bn2i, bn2a, pool);
  fused_kernel<0, true ><<<196, 512, 0, stream>>>(x,  cent1, cn1, lut1T, bn1i, bn1a, y1);
  fused_kernel<1, false><<<196, 512, 0, stream>>>(y1, cent2, cn2, lut2T, bn2i, bn2a, y2);
  pool_kernel<<<dim3(16, 7), 256, 0, stream>>>(y2, pool);
  se_kernel<<<16, 256, 0, stream>>>(pool, sw1, sb1, sw2, sb2, scale);
  final_kernel<<<12544, 256, 0, stream>>>(y2, scale, x, out);
}

// Round 3
// 657.176 us; speedup vs baseline: 1.1911x; 1.1911x over previous
//
#include <hip/hip_runtime.h>
#include <cstdint>
#include <cstddef>

typedef _Float16 f16;
typedef _Float16 f16x8 __attribute__((ext_vector_type(8)));
typedef float f32x4 __attribute__((ext_vector_type(4)));

// ---------------- helpers ----------------

__device__ __forceinline__ uint32_t packh2(float a, float b) {
  f16 ha = (f16)a, hb = (f16)b;
  uint16_t ua = __builtin_bit_cast(uint16_t, ha);
  uint16_t ub = __builtin_bit_cast(uint16_t, hb);
  return (uint32_t)ua | ((uint32_t)ub << 16);
}

// ---------------- prep: LUT (K-tiled) fp16, centroid sq-norms, BN consts, pool zero --------
// NEW layout: lut[kt][o][kk]  (kt = K-chunk of 64, o = output channel, kk = ck&63)
// -> the 256x64 panel a block consumes per K-iter is CONTIGUOUS (32 KB), so
//    B-fragment loads hit 16 lines in a 2 KB window instead of 16 lines at
//    8 KB stride (which thrashed L1 sets and hotspotted L2 channels).
__global__ __launch_bounds__(256) void prep_kernel(
    const float* __restrict__ cent1, const float* __restrict__ wsub1,
    const float* __restrict__ cent2, const float* __restrict__ wsub2,
    const float* __restrict__ g1, const float* __restrict__ be1,
    const float* __restrict__ mu1, const float* __restrict__ va1,
    const float* __restrict__ g2, const float* __restrict__ be2,
    const float* __restrict__ mu2, const float* __restrict__ va2,
    f16* __restrict__ lut1, f16* __restrict__ lut2,
    float* __restrict__ cn1, float* __restrict__ cn2,
    float* __restrict__ bn1i, float* __restrict__ bn1a,
    float* __restrict__ bn2i, float* __restrict__ bn2a,
    float* __restrict__ pool)
{
  int bx = blockIdx.x, t = threadIdx.x;
  if (bx < 8192) {
    int conv = bx >> 12, ck = bx & 4095, c = ck >> 4;
    const float* cent = conv ? cent2 : cent1;
    const float* wsub = conv ? wsub2 : wsub1;
    f16* lut = conv ? lut2 : lut1;
    float s = 0.f;
#pragma unroll
    for (int sv = 0; sv < 9; ++sv)
      s += cent[ck*9 + sv] * wsub[(c*9 + sv)*256 + t];
    lut[(size_t)(ck >> 6)*16384 + (size_t)t*64 + (ck & 63)] = (f16)s;
  } else {
    for (int j = 0; j < 16; ++j) {
      int ck = j*256 + t;
      float s1 = 0.f, s2 = 0.f;
#pragma unroll
      for (int sv = 0; sv < 9; ++sv) {
        float a = cent1[ck*9 + sv]; s1 += a*a;
        float b = cent2[ck*9 + sv]; s2 += b*b;
      }
      cn1[ck] = s1; cn2[ck] = s2;
      pool[ck] = 0.f;                 // ws is re-poisoned 0xAA every launch
    }
    float i1 = g1[t] * rsqrtf(va1[t] + 1e-5f);
    bn1i[t] = i1; bn1a[t] = be1[t] - mu1[t]*i1;
    float i2 = g2[t] * rsqrtf(va2[t] + 1e-5f);
    bn2i[t] = i2; bn2a[t] = be2[t] - mu2[t]*i2;
  }
}

// ---------------- fused attn+GEMM layer ----------------
// Never materializes the [12544, 4096] attn matrix. Block = 64 output rows
// (positions) x all 256 outputs, K = 4096 in 64 chunks of 64 (4 ch x 16 cw).
// Per chunk: 512 threads produce the 64x64 fp16 attn tile into LDS (XOR
// swizzled, double buffered); 8 waves (2x4) consume it with
// mfma_f32_16x16x32_f16. B panels (contiguous 32 KB per chunk in the K-tiled
// lut) are REGISTER double-buffered: loadB(kt+1) issues before compute(kt),
// so B latency hides under a full MFMA+softmax phase. One barrier per chunk.
// SRC==0: src is x, NCHW [16][256][28][28]. SRC==1: src is y1, NHWC [12544][256].
template<int SRC, bool RELU>
__global__ __launch_bounds__(512, 2) void fused_kernel(
    const float* __restrict__ src, const float* __restrict__ cent,
    const float* __restrict__ cn, const f16* __restrict__ lut,
    const float* __restrict__ inv, const float* __restrict__ add,
    float* __restrict__ Y)
{
  __shared__ __align__(16) f16 As[2][64*64];    // 2 x 8 KB double buffer

  int t = threadIdx.x;
  int lane = t & 63, wave = t >> 6;
  int wm = wave >> 2, wn = wave & 3;            // 2x4 wave grid, tile 32x64
  int fm = lane & 15, fq = lane >> 4;

  // attn producer role: pair (pos, cg) split across 2 adjacent lanes (half)
  int pos = t >> 3;             // 0..63
  int cg  = (t >> 1) & 3;       // channel within 4-channel K-chunk
  int half = t & 1;             // codeword half: k = half*8 .. half*8+7
  int row0 = blockIdx.x * 64;
  int P = row0 + pos;
  int b = P / 784, n = P % 784, h = n / 28, w = n % 28;

  // patch source: single base pointer + 9 int offsets (element units)
  const float* pbase = (SRC == 0) ? src + ((size_t)b*256 + cg)*784
                                  : src + ((size_t)b*784)*256 + cg;
  int offc[9]; float msk[9];
#pragma unroll
  for (int dh = 0; dh < 3; ++dh)
#pragma unroll
    for (int dw = 0; dw < 3; ++dw) {
      int hh = h + dh - 1, ww = w + dw - 1;
      bool ok = (hh >= 0) && (hh < 28) && (ww >= 0) && (ww < 28);
      int o = ok ? (hh*28 + ww) : 0;
      offc[dh*3+dw] = (SRC == 0) ? o : o*256;
      msk[dh*3+dw] = ok ? 1.f : 0.f;
    }
  const int pstep = (SRC == 0) ? 4*784 : 4;     // advance to channel c+4
  const float* cb  = cent + (size_t)cg*144 + half*72;  // + kt*576 per chunk
  const float* cnp = cn + cg*16 + half*8;              // + kt*64 per chunk

  f32x4 acc[2][4] = {};

  auto attn_store = [&](int kt, const float* pn, f16* Ab) {
    float p[9];
#pragma unroll
    for (int s = 0; s < 9; ++s) p[s] = pn[s]*msk[s];
    const float* ce = cb + (size_t)kt*576;
    float e[8];
    // two half-batches of 4 codewords (caps register pressure: 9 f32x4 live)
#pragma unroll
    for (int kh = 0; kh < 2; ++kh) {
      f32x4 cr[9];
#pragma unroll
      for (int i = 0; i < 9; ++i) cr[i] = *(const f32x4*)(ce + kh*36 + i*4);
      f32x4 cc = *(const f32x4*)(cnp + kt*64 + kh*4);
#pragma unroll
      for (int k = 0; k < 4; ++k) {
        float dot = 0.f;
#pragma unroll
        for (int s = 0; s < 9; ++s) {
          int i = k*9 + s;                      // compile-time after unroll
          dot += p[s]*cr[i >> 2][i & 3];
        }
        e[kh*4 + k] = 2.f*dot - cc[k];          // ||p||^2 cancels in softmax
      }
    }
    float mx = e[0];
#pragma unroll
    for (int k = 1; k < 8; ++k) mx = fmaxf(mx, e[k]);
    mx = fmaxf(mx, __shfl_xor(mx, 1));          // pair-combine (same wave)
    float sum = 0.f;
#pragma unroll
    for (int k = 0; k < 8; ++k) { e[k] = __expf(e[k] - mx); sum += e[k]; }
    sum += __shfl_xor(sum, 1);
    float rs = 1.f/sum;
    uint32_t w0 = packh2(e[0]*rs, e[1]*rs);
    uint32_t w1 = packh2(e[2]*rs, e[3]*rs);
    uint32_t w2 = packh2(e[4]*rs, e[5]*rs);
    uint32_t w3 = packh2(e[6]*rs, e[7]*rs);
    // logical chunk cg*2+half of row pos, stored at physical chunk ^(pos&7)
    int chunk = (cg*2 + half) ^ (pos & 7);
    *(uint4*)(Ab + pos*64 + chunk*8) = make_uint4(w0, w1, w2, w3);
  };

  // B-panel fragment loads: contiguous K-tiled layout [kt][256][64]
  auto loadB = [&](int kt, f16x8* bf) {
    const f16* bp = lut + (size_t)kt*16384 + (size_t)(wn*64 + fm)*64 + fq*8;
#pragma unroll
    for (int nn = 0; nn < 4; ++nn) {
      bf[nn*2 + 0] = *(const f16x8*)(bp + nn*1024);        // ks=0
      bf[nn*2 + 1] = *(const f16x8*)(bp + nn*1024 + 32);   // ks=1
    }
  };

  auto compute = [&](const f16* Ab, const f16x8* bf) {
#pragma unroll
    for (int ks = 0; ks < 2; ++ks) {
      int co = ((ks*4 + fq) ^ (fm & 7)) * 8;
      f16x8 af[2];
#pragma unroll
      for (int m = 0; m < 2; ++m)
        af[m] = *(const f16x8*)(Ab + (wm*32 + m*16 + fm)*64 + co);
#pragma unroll
      for (int m = 0; m < 2; ++m)
#pragma unroll
        for (int nn = 0; nn < 4; ++nn)
          acc[m][nn] = __builtin_amdgcn_mfma_f32_16x16x32_f16(af[m], bf[nn*2+ks], acc[m][nn], 0, 0, 0);
    }
  };

  f16* A0 = &As[0][0];
  f16* A1 = &As[1][0];
  f16x8 bfA[8], bfB[8];
  {
    float pn[9];
#pragma unroll
    for (int s = 0; s < 9; ++s) pn[s] = pbase[offc[s]];
    attn_store(0, pn, A0);
    loadB(0, bfA);
  }
#pragma unroll 1
  for (int kt2 = 0; kt2 < 32; ++kt2) {
    int kt = kt2*2;
    __syncthreads();                   // A(kt) visible; A1 free
    {
      loadB(kt + 1, bfB);              // B latency hides under compute+softmax
      float pn[9];
#pragma unroll
      for (int s = 0; s < 9; ++s) pn[s] = pbase[offc[s] + (kt + 1)*pstep];
      compute(A0, bfA);
      attn_store(kt + 1, pn, A1);
    }
    __syncthreads();                   // A(kt+1) visible; A0 free
    if (kt2 < 31) {
      loadB(kt + 2, bfA);
      float pn[9];
#pragma unroll
      for (int s = 0; s < 9; ++s) pn[s] = pbase[offc[s] + (kt + 2)*pstep];
      compute(A1, bfB);
      attn_store(kt + 2, pn, A0);
    } else {
      compute(A1, bfB);
    }
  }

  // epilogue: C/D layout col=lane&15, row=fq*4+r; fused BN (+ReLU)
#pragma unroll
  for (int nn = 0; nn < 4; ++nn) {
    int colg = wn*64 + nn*16 + fm;
    float iv = inv[colg], ad = add[colg];
#pragma unroll
    for (int m = 0; m < 2; ++m) {
      int rowg = row0 + wm*32 + m*16 + fq*4;
#pragma unroll
      for (int r = 0; r < 4; ++r) {
        float v = acc[m][nn][r]*iv + ad;
        if (RELU) v = fmaxf(v, 0.f);
        Y[(size_t)(rowg + r)*256 + colg] = v;
      }
    }
  }
}

// ---------------- global average pool (partial sums, atomics) ----------------
__global__ __launch_bounds__(256) void pool_kernel(const float* __restrict__ y2,
                                                   float* __restrict__ pool)
{
  int b = blockIdx.x, t = threadIdx.x;
  int r0 = blockIdx.y * 112;
  float s = 0.f;
  for (int r = 0; r < 112; ++r)
    s += y2[((size_t)b*784 + r0 + r)*256 + t];
  atomicAdd(&pool[b*256 + t], s);
}

// ---------------- SE MLP: scale = sigmoid(relu(mean @ w1 + b1) @ w2 + b2) ----------------
__global__ __launch_bounds__(256) void se_kernel(
    const float* __restrict__ pool, const float* __restrict__ w1, const float* __restrict__ b1,
    const float* __restrict__ w2, const float* __restrict__ b2, float* __restrict__ scale)
{
  __shared__ float m[256];
  __shared__ float hbuf[16];
  int b = blockIdx.x, t = threadIdx.x;
  m[t] = pool[b*256 + t] * (1.f/784.f);
  __syncthreads();
  if (t < 16) {
    float a = b1[t];
    for (int o = 0; o < 256; ++o) a += m[o]*w1[o*16 + t];
    hbuf[t] = fmaxf(a, 0.f);
  }
  __syncthreads();
  float a = b2[t];
#pragma unroll
  for (int jj = 0; jj < 16; ++jj) a += hbuf[jj]*w2[jj*256 + t];
  scale[b*256 + t] = 1.f/(1.f + __expf(-a));
}

// ---------------- final: out = relu(y2 * scale + x), NCHW ----------------
__global__ __launch_bounds__(256) void final_kernel(
    const float* __restrict__ y2, const float* __restrict__ scale,
    const float* __restrict__ x, float* __restrict__ out)
{
  int idx = blockIdx.x*256 + threadIdx.x;
  int b = idx / 200704, rem = idx % 200704;
  int o = rem / 784, hw = rem % 784;
  float v = y2[((size_t)b*784 + hw)*256 + o]*scale[b*256 + o] + x[idx];
  out[idx] = fmaxf(v, 0.f);
}

// ---------------- launch ----------------
extern "C" void kernel_launch(void* const* d_in, const int* in_sizes, int n_in,
                              void* d_out, int out_size, void* d_ws, size_t ws_size,
                              hipStream_t stream) {
  const float* x     = (const float*)d_in[0];
  const float* cent1 = (const float*)d_in[1];
  const float* wsub1 = (const float*)d_in[2];
  const float* g1    = (const float*)d_in[3];
  const float* be1   = (const float*)d_in[4];
  const float* mu1   = (const float*)d_in[5];
  const float* va1   = (const float*)d_in[6];
  const float* cent2 = (const float*)d_in[7];
  const float* wsub2 = (const float*)d_in[8];
  const float* g2    = (const float*)d_in[9];
  const float* be2   = (const float*)d_in[10];
  const float* mu2   = (const float*)d_in[11];
  const float* va2   = (const float*)d_in[12];
  const float* sw1   = (const float*)d_in[13];
  const float* sb1   = (const float*)d_in[14];
  const float* sw2   = (const float*)d_in[15];
  const float* sb2   = (const float*)d_in[16];
  float* out = (float*)d_out;

  char* ws = (char*)d_ws;
  // attn region (first ~102.8 MB) unused — offsets kept to minimize churn
  f16*   lut1  = (f16*)(ws + 102760448);          // 2 MB (K-tiled [64][256][64])
  f16*   lut2  = (f16*)(ws + 104857600);          // 2 MB
  float* y1    = (float*)(ws + 106954752);        // 12,845,056
  float* y2    = (float*)(ws + 119799808);        // 12,845,056
  float* cn1   = (float*)(ws + 132644864);        // 16 KB
  float* cn2   = (float*)(ws + 132661248);        // 16 KB
  float* bn1i  = (float*)(ws + 132677632);
  float* bn1a  = (float*)(ws + 132678656);
  float* bn2i  = (float*)(ws + 132679680);
  float* bn2a  = (float*)(ws + 132680704);
  float* pool  = (float*)(ws + 132681728);        // 16 KB
  float* scale = (float*)(ws + 132698112);        // 16 KB  (end ~126.6 MiB)

  prep_kernel<<<8193, 256, 0, stream>>>(cent1, wsub1, cent2, wsub2,
                                        g1, be1, mu1, va1, g2, be2, mu2, va2,
                                        lut1, lut2, cn1, cn2,
                                        bn1i, bn1a, bn2i, bn2a, pool);
  fused_kernel<0, true ><<<196, 512, 0, stream>>>(x,  cent1, cn1, lut1, bn1i, bn1a, y1);
  fused_kernel<1, false><<<196, 512, 0, stream>>>(y1, cent2, cn2, lut2, bn2i, bn2a, y2);
  pool_kernel<<<dim3(16, 7), 256, 0, stream>>>(y2, pool);
  se_kernel<<<16, 256, 0, stream>>>(pool, sw1, sb1, sw2, sb2, scale);
  final_kernel<<<12544, 256, 0, stream>>>(y2, scale, x, out);
}

// Round 4
// 396.299 us; speedup vs baseline: 1.9752x; 1.6583x over previous
//
#include <hip/hip_runtime.h>
#include <cstdint>
#include <cstddef>

typedef _Float16 f16;
typedef _Float16 f16x8 __attribute__((ext_vector_type(8)));
typedef float f32x4 __attribute__((ext_vector_type(4)));

// ---------------- helpers ----------------

__device__ __forceinline__ void gload16(const void* g, void* l) {
  // async global->LDS, 16B per lane; LDS dest must be wave-uniform base + lane*16
  __builtin_amdgcn_global_load_lds((const __attribute__((address_space(1))) void*)g,
                                   (__attribute__((address_space(3))) void*)l, 16, 0, 0);
}

__device__ __forceinline__ uint32_t packh2(float a, float b) {
  f16 ha = (f16)a, hb = (f16)b;
  uint16_t ua = __builtin_bit_cast(uint16_t, ha);
  uint16_t ub = __builtin_bit_cast(uint16_t, hb);
  return (uint32_t)ua | ((uint32_t)ub << 16);
}

// ---------------- prep ----------------
// lut: K-tiled AND pre-swizzled for linear global_load_lds staging:
//   logical element (kt, o, kk) stored at [kt][o][ ((kk>>3)^(o&7))*8 + (kk&7) ]
//   (16B-chunk XOR by row&7 -> conflict-free ds_read_b128 in fused kernel).
// centK[conv][kt][640]: per-chunk centroids pre-scaled by 2 (576 floats,
//   layout [cg*2+half][8 cw][9]) followed by 64 cn values ([cg*16+half*8+k]).
__global__ __launch_bounds__(256) void prep_kernel(
    const float* __restrict__ cent1, const float* __restrict__ wsub1,
    const float* __restrict__ cent2, const float* __restrict__ wsub2,
    const float* __restrict__ g1, const float* __restrict__ be1,
    const float* __restrict__ mu1, const float* __restrict__ va1,
    const float* __restrict__ g2, const float* __restrict__ be2,
    const float* __restrict__ mu2, const float* __restrict__ va2,
    f16* __restrict__ lut1, f16* __restrict__ lut2,
    float* __restrict__ centK1, float* __restrict__ centK2,
    float* __restrict__ bn1i, float* __restrict__ bn1a,
    float* __restrict__ bn2i, float* __restrict__ bn2a,
    float* __restrict__ pool)
{
  int bx = blockIdx.x, t = threadIdx.x;
  if (bx < 8192) {
    int conv = bx >> 12, ck = bx & 4095, c = ck >> 4;
    const float* cent = conv ? cent2 : cent1;
    const float* wsub = conv ? wsub2 : wsub1;
    f16* lut = conv ? lut2 : lut1;
    float s = 0.f;
#pragma unroll
    for (int sv = 0; sv < 9; ++sv)
      s += cent[ck*9 + sv] * wsub[(c*9 + sv)*256 + t];
    int kk = ck & 63;
    lut[(size_t)(ck >> 6)*16384 + (size_t)t*64 + (((kk >> 3) ^ (t & 7))*8) + (kk & 7)] = (f16)s;
  } else if (bx < 8320) {
    int base = bx - 8192;
    int conv = base >> 6, kt = base & 63;
    const float* cent = conv ? cent2 : cent1;
    float* centK = conv ? centK2 : centK1;
    for (int f = t; f < 640; f += 256) {
      float v;
      if (f < 576) {
        int g = f / 72, w = f % 72;           // g = cg*2+half
        int cg = g >> 1, hf = g & 1;
        int kl = w / 9, s = w % 9;
        int c = kt*4 + cg, k = hf*8 + kl;
        v = 2.f * cent[(c*16 + k)*9 + s];
      } else {
        int j = f - 576;
        int c = kt*4 + (j >> 4), k = j & 15;
        float ss = 0.f;
#pragma unroll
        for (int s = 0; s < 9; ++s) { float a = cent[(c*16 + k)*9 + s]; ss += a*a; }
        v = ss;
      }
      centK[(size_t)kt*640 + f] = v;
    }
  } else {
    for (int j = 0; j < 16; ++j)
      pool[j*256 + t] = 0.f;                  // ws is re-poisoned 0xAA every launch
    float i1 = g1[t] * rsqrtf(va1[t] + 1e-5f);
    bn1i[t] = i1; bn1a[t] = be1[t] - mu1[t]*i1;
    float i2 = g2[t] * rsqrtf(va2[t] + 1e-5f);
    bn2i[t] = i2; bn2a[t] = be2[t] - mu2[t]*i2;
  }
}

// ---------------- fused attn+GEMM layer ----------------
// Block = 64 output rows (positions) x 256 outputs, K = 4096 in 64 chunks of
// 64 (4 ch x 16 cw). All per-chunk operands live in LDS, staged ASYNC via
// global_load_lds one chunk ahead (drained by the phase barrier => zero
// in-phase vector-load waits except the 9 pn patch floats, which are issued
// first after the barrier and consumed after compute):
//   As[2]: 64x64 fp16 attn tile, produced in-block (XOR swizzle by row&7)
//   Bs[2]: 256x64 fp16 LUT panel (32 KB), source pre-swizzled by prep
//   Cs[2]: 640 f32 centroids(x2)+cn, broadcast ds_reads in attn phase
// 8 waves (2x4), wave tile 32x64, mfma_f32_16x16x32_f16, one barrier/chunk.
// SRC==0: src is x, NCHW [16][256][28][28]. SRC==1: src is y1, NHWC [12544][256].
template<int SRC, bool RELU>
__global__ __launch_bounds__(512, 2) void fused_kernel(
    const float* __restrict__ src, const float* __restrict__ centK,
    const f16* __restrict__ lut,
    const float* __restrict__ inv, const float* __restrict__ add,
    float* __restrict__ Y)
{
  __shared__ __align__(16) f16 As[2][4096];     // 2 x 8 KB
  __shared__ __align__(16) f16 Bs[2][16384];    // 2 x 32 KB
  __shared__ __align__(16) float Cs[2][640];    // 2 x 2.5 KB

  int t = threadIdx.x;
  int lane = t & 63, wave = t >> 6;
  int wm = wave >> 2, wn = wave & 3;            // 2x4 wave grid, tile 32x64
  int fm = lane & 15, fq = lane >> 4;

  // attn producer role: pair (pos, cg) split across 2 adjacent lanes (half)
  int pos = t >> 3;             // 0..63
  int cg  = (t >> 1) & 3;       // channel within 4-channel K-chunk
  int hf  = t & 1;              // codeword half: k = hf*8 .. hf*8+7
  int row0 = blockIdx.x * 64;
  int P = row0 + pos;
  int b = P / 784, n = P % 784, h = n / 28, w = n % 28;

  const float* pbase = (SRC == 0) ? src + ((size_t)b*256 + cg)*784
                                  : src + ((size_t)b*784)*256 + cg;
  int offc[9]; float msk[9];
#pragma unroll
  for (int dh = 0; dh < 3; ++dh)
#pragma unroll
    for (int dw = 0; dw < 3; ++dw) {
      int hh = h + dh - 1, ww = w + dw - 1;
      bool ok = (hh >= 0) && (hh < 28) && (ww >= 0) && (ww < 28);
      int o = ok ? (hh*28 + ww) : 0;
      offc[dh*3+dw] = (SRC == 0) ? o : o*256;
      msk[dh*3+dw] = ok ? 1.f : 0.f;
    }
  const int pstep = (SRC == 0) ? 4*784 : 4;     // advance to channel c+4

  f32x4 acc[2][4] = {};

  // async stages (linear LDS dest; swizzle pre-baked in global layouts)
  auto stageB = [&](int kt) {
    const f16* sp = lut + (size_t)kt*16384 + t*8;
    f16* dp = &Bs[kt & 1][0] + t*8;
#pragma unroll
    for (int i = 0; i < 4; ++i) gload16(sp + i*4096, dp + i*4096);
  };
  auto stageC = [&](int kt) {
    if (t < 160) gload16(centK + (size_t)kt*640 + t*4, &Cs[kt & 1][0] + t*4);
  };

  auto attn_store = [&](const float* Cb, const float* pn, f16* Ab) {
    float p[9];
#pragma unroll
    for (int s = 0; s < 9; ++s) p[s] = pn[s]*msk[s];
    const float* ce  = Cb + (cg*2 + hf)*72;        // 2x-scaled centroids (LDS)
    const float* cnl = Cb + 576 + cg*16 + hf*8;    // cn (LDS)
    float e[8];
#pragma unroll
    for (int kh = 0; kh < 2; ++kh) {
      f32x4 cr[9];
#pragma unroll
      for (int i = 0; i < 9; ++i) cr[i] = *(const f32x4*)(ce + kh*36 + i*4);
      f32x4 cc = *(const f32x4*)(cnl + kh*4);
#pragma unroll
      for (int k = 0; k < 4; ++k) {
        float dot = 0.f;
#pragma unroll
        for (int s = 0; s < 9; ++s) {
          int i = k*9 + s;                         // compile-time after unroll
          dot += p[s]*cr[i >> 2][i & 3];
        }
        e[kh*4 + k] = dot - cc[k];                 // cent pre-scaled by 2
      }
    }
    float mx = e[0];
#pragma unroll
    for (int k = 1; k < 8; ++k) mx = fmaxf(mx, e[k]);
    mx = fmaxf(mx, __shfl_xor(mx, 1));             // pair-combine (same wave)
    float sum = 0.f;
#pragma unroll
    for (int k = 0; k < 8; ++k) { e[k] = __expf(e[k] - mx); sum += e[k]; }
    sum += __shfl_xor(sum, 1);
    float rs = 1.f/sum;
    uint32_t w0 = packh2(e[0]*rs, e[1]*rs);
    uint32_t w1 = packh2(e[2]*rs, e[3]*rs);
    uint32_t w2 = packh2(e[4]*rs, e[5]*rs);
    uint32_t w3 = packh2(e[6]*rs, e[7]*rs);
    int chunk = (cg*2 + hf) ^ (pos & 7);           // XOR swizzle by row&7
    *(uint4*)(Ab + pos*64 + chunk*8) = make_uint4(w0, w1, w2, w3);
  };

  auto compute = [&](const f16* Ab, const f16* Bb) {
#pragma unroll
    for (int ks = 0; ks < 2; ++ks) {
      int co = ((ks*4 + fq) ^ (fm & 7)) * 8;       // same swizzle for A and B
      f16x8 af[2];
#pragma unroll
      for (int m = 0; m < 2; ++m)
        af[m] = *(const f16x8*)(Ab + (wm*32 + m*16 + fm)*64 + co);
      f16x8 bf[4];
#pragma unroll
      for (int nn = 0; nn < 4; ++nn)
        bf[nn] = *(const f16x8*)(Bb + (wn*64 + nn*16 + fm)*64 + co);
#pragma unroll
      for (int m = 0; m < 2; ++m)
#pragma unroll
        for (int nn = 0; nn < 4; ++nn)
          acc[m][nn] = __builtin_amdgcn_mfma_f32_16x16x32_f16(af[m], bf[nn], acc[m][nn], 0, 0, 0);
    }
  };

  // prologue: stage chunk 0 operands + cent(1); compute A(0)
  {
    stageC(0);
    stageC(1);
    stageB(0);
    float pn[9];
#pragma unroll
    for (int s = 0; s < 9; ++s) pn[s] = pbase[offc[s]];
    __syncthreads();                    // C0/C1/B0 landed (vmcnt drain), pn too
    attn_store(&Cs[0][0], pn, &As[0][0]);
  }
#pragma unroll 1
  for (int kt = 0; kt < 64; ++kt) {
    __syncthreads();                    // A(kt),B(kt) visible; C(kt+1) landed
    float pn[9];
    if (kt < 63) {
#pragma unroll
      for (int s = 0; s < 9; ++s) pn[s] = pbase[offc[s] + (kt + 1)*pstep];  // issue FIRST
      stageB(kt + 1);                   // async, drained by next barrier
      if (kt < 62) stageC(kt + 2);
    }
    compute(&As[kt & 1][0], &Bs[kt & 1][0]);
    if (kt < 63) attn_store(&Cs[(kt + 1) & 1][0], pn, &As[(kt + 1) & 1][0]);
  }

  // epilogue: C/D layout col=lane&15, row=fq*4+r; fused BN (+ReLU)
#pragma unroll
  for (int nn = 0; nn < 4; ++nn) {
    int colg = wn*64 + nn*16 + fm;
    float iv = inv[colg], ad = add[colg];
#pragma unroll
    for (int m = 0; m < 2; ++m) {
      int rowg = row0 + wm*32 + m*16 + fq*4;
#pragma unroll
      for (int r = 0; r < 4; ++r) {
        float v = acc[m][nn][r]*iv + ad;
        if (RELU) v = fmaxf(v, 0.f);
        Y[(size_t)(rowg + r)*256 + colg] = v;
      }
    }
  }
}

// ---------------- global average pool (partial sums, atomics) ----------------
__global__ __launch_bounds__(256) void pool_kernel(const float* __restrict__ y2,
                                                   float* __restrict__ pool)
{
  int b = blockIdx.x, t = threadIdx.x;
  int r0 = blockIdx.y * 112;
  float s = 0.f;
  for (int r = 0; r < 112; ++r)
    s += y2[((size_t)b*784 + r0 + r)*256 + t];
  atomicAdd(&pool[b*256 + t], s);
}

// ---------------- SE MLP: scale = sigmoid(relu(mean @ w1 + b1) @ w2 + b2) ----------------
__global__ __launch_bounds__(256) void se_kernel(
    const float* __restrict__ pool, const float* __restrict__ w1, const float* __restrict__ b1,
    const float* __restrict__ w2, const float* __restrict__ b2, float* __restrict__ scale)
{
  __shared__ float m[256];
  __shared__ float hbuf[16];
  int b = blockIdx.x, t = threadIdx.x;
  m[t] = pool[b*256 + t] * (1.f/784.f);
  __syncthreads();
  if (t < 16) {
    float a = b1[t];
    for (int o = 0; o < 256; ++o) a += m[o]*w1[o*16 + t];
    hbuf[t] = fmaxf(a, 0.f);
  }
  __syncthreads();
  float a = b2[t];
#pragma unroll
  for (int jj = 0; jj < 16; ++jj) a += hbuf[jj]*w2[jj*256 + t];
  scale[b*256 + t] = 1.f/(1.f + __expf(-a));
}

// ---------------- final: out = relu(y2 * scale + x), NCHW ----------------
__global__ __launch_bounds__(256) void final_kernel(
    const float* __restrict__ y2, const float* __restrict__ scale,
    const float* __restrict__ x, float* __restrict__ out)
{
  int idx = blockIdx.x*256 + threadIdx.x;
  int b = idx / 200704, rem = idx % 200704;
  int o = rem / 784, hw = rem % 784;
  float v = y2[((size_t)b*784 + hw)*256 + o]*scale[b*256 + o] + x[idx];
  out[idx] = fmaxf(v, 0.f);
}

// ---------------- launch ----------------
extern "C" void kernel_launch(void* const* d_in, const int* in_sizes, int n_in,
                              void* d_out, int out_size, void* d_ws, size_t ws_size,
                              hipStream_t stream) {
  const float* x     = (const float*)d_in[0];
  const float* cent1 = (const float*)d_in[1];
  const float* wsub1 = (const float*)d_in[2];
  const float* g1    = (const float*)d_in[3];
  const float* be1   = (const float*)d_in[4];
  const float* mu1   = (const float*)d_in[5];
  const float* va1   = (const float*)d_in[6];
  const float* cent2 = (const float*)d_in[7];
  const float* wsub2 = (const float*)d_in[8];
  const float* g2    = (const float*)d_in[9];
  const float* be2   = (const float*)d_in[10];
  const float* mu2   = (const float*)d_in[11];
  const float* va2   = (const float*)d_in[12];
  const float* sw1   = (const float*)d_in[13];
  const float* sb1   = (const float*)d_in[14];
  const float* sw2   = (const float*)d_in[15];
  const float* sb2   = (const float*)d_in[16];
  float* out = (float*)d_out;

  char* ws = (char*)d_ws;
  float* centK1 = (float*)(ws + 0);               // 64*640*4 = 163,840
  float* centK2 = (float*)(ws + 163840);          // 163,840
  f16*   lut1  = (f16*)(ws + 102760448);          // 2 MB (K-tiled + swizzled)
  f16*   lut2  = (f16*)(ws + 104857600);          // 2 MB
  float* y1    = (float*)(ws + 106954752);        // 12,845,056
  float* y2    = (float*)(ws + 119799808);        // 12,845,056
  float* bn1i  = (float*)(ws + 132677632);
  float* bn1a  = (float*)(ws + 132678656);
  float* bn2i  = (float*)(ws + 132679680);
  float* bn2a  = (float*)(ws + 132680704);
  float* pool  = (float*)(ws + 132681728);        // 16 KB
  float* scale = (float*)(ws + 132698112);        // 16 KB  (end ~126.6 MiB)

  prep_kernel<<<8321, 256, 0, stream>>>(cent1, wsub1, cent2, wsub2,
                                        g1, be1, mu1, va1, g2, be2, mu2, va2,
                                        lut1, lut2, centK1, centK2,
                                        bn1i, bn1a, bn2i, bn2a, pool);
  fused_kernel<0, true ><<<196, 512, 0, stream>>>(x,  centK1, lut1, bn1i, bn1a, y1);
  fused_kernel<1, false><<<196, 512, 0, stream>>>(y1, centK2, lut2, bn2i, bn2a, y2);
  pool_kernel<<<dim3(16, 7), 256, 0, stream>>>(y2, pool);
  se_kernel<<<16, 256, 0, stream>>>(pool, sw1, sb1, sw2, sb2, scale);
  final_kernel<<<12544, 256, 0, stream>>>(y2, scale, x, out);
}